// Round 9
// baseline (226.125 us; speedup 1.0000x reference)
//
#include <hip/hip_runtime.h>
#include <math.h>

#define S_N 8
#define U_N 8
#define K_N 6
#define NNEG 17
#define ZDIM 64
#define CDIM 256
#define LEN 512
#define TDIM (LEN + K_N)   // 518

typedef __attribute__((ext_vector_type(8))) short short8;
typedef __attribute__((ext_vector_type(4))) short short4v;
typedef __attribute__((ext_vector_type(4))) float f32x4;

__device__ __forceinline__ short f2bf(float x) {
    unsigned u = __builtin_bit_cast(unsigned, x);
    return (short)((u + 0x7fffu + ((u >> 16) & 1u)) >> 16);   // RNE
}
__device__ __forceinline__ float bf2f(short h) {
    unsigned u = ((unsigned)(unsigned short)h) << 16;
    return __builtin_bit_cast(float, u);
}
__device__ __forceinline__ short8 cvt8(f32x4 a, f32x4 b) {
    short8 r;
    r[0] = f2bf(a[0]); r[1] = f2bf(a[1]); r[2] = f2bf(a[2]); r[3] = f2bf(a[3]);
    r[4] = f2bf(b[0]); r[5] = f2bf(b[1]); r[6] = f2bf(b[2]); r[7] = f2bf(b[3]);
    return r;
}
// quad butterfly sum via DPP (pure VALU): quad_perm [1,0,3,2]=0xB1, [2,3,0,1]=0x4E
__device__ __forceinline__ float qsum(float x) {
    int i = __builtin_bit_cast(int, x);
    float y = x + __builtin_bit_cast(float, __builtin_amdgcn_mov_dpp(i, 0xB1, 0xF, 0xF, true));
    int i2 = __builtin_bit_cast(int, y);
    return y + __builtin_bit_cast(float, __builtin_amdgcn_mov_dpp(i2, 0x4E, 0xF, 0xF, true));
}

// ============ Kernel 0: W f32 -> bf16 (once) ============
__global__ __launch_bounds__(256) void cpc_wcvt(const float* __restrict__ Wg,
                                                short* __restrict__ wbf)
{
    int i4 = (blockIdx.x * 256 + threadIdx.x) * 4;   // < 98304
    f32x4 v = *(const f32x4*)(Wg + i4);
    short4v h;
    h.x = f2bf(v[0]); h.y = f2bf(v[1]); h.z = f2bf(v[2]); h.w = f2bf(v[3]);
    *(short4v*)(wbf + i4) = h;
}

// ============ Kernel 1: Wc GEMM -> workspace (bf16, pre-scaled by 1/8) ============
// grid = 64 su * 16 ltiles = 1024 blocks, 128 threads (2 waves, 32 l-rows).
// B-fragments loaded straight from wbf (W[k] bf16 = 32KB, L1/L2-resident).
__global__ __launch_bounds__(128) void cpc_gemm(
    const float* __restrict__ cg_, const short* __restrict__ wbf,
    const float* __restrict__ bg, short* __restrict__ Wcg)
{
    __shared__ float wc[32][68];

    const int tid = threadIdx.x;
    const int bid = blockIdx.x;
    const int su  = bid >> 4;
    const int lt16 = bid & 15;
    const int l0  = lt16 * 32;

    const int wave   = tid >> 6;
    const int lane   = tid & 63;
    const int lane15 = lane & 15;
    const int lgrp   = lane >> 4;

    // A preload once (named regs)
    short8 af0, af1, af2, af3, af4, af5, af6, af7;
    {
        const int lrow = l0 + wave * 16 + lane15;
        const float* arow = cg_ + ((size_t)(su * TDIM + lrow)) * CDIM;
#define LDA(KC, AF) { \
        f32x4 a0_ = __builtin_nontemporal_load((const f32x4*)(arow + (KC) * 32 + lgrp * 8)); \
        f32x4 a1_ = __builtin_nontemporal_load((const f32x4*)(arow + (KC) * 32 + lgrp * 8 + 4)); \
        AF = cvt8(a0_, a1_); }
        LDA(0, af0) LDA(1, af1) LDA(2, af2) LDA(3, af3)
        LDA(4, af4) LDA(5, af5) LDA(6, af6) LDA(7, af7)
#undef LDA
    }

    for (int k = 0; k < K_N; ++k) {
        f32x4 acc0 = {0.f,0.f,0.f,0.f}, acc1 = {0.f,0.f,0.f,0.f};
        f32x4 acc2 = {0.f,0.f,0.f,0.f}, acc3 = {0.f,0.f,0.f,0.f};
        const short* wp0 = wbf + ((k * 64 + lane15) << 8) + lgrp * 8;
#define DOKC(KC, AF) { \
        short8 b0 = *(const short8*)(wp0 + (KC) * 32); \
        short8 b1 = *(const short8*)(wp0 + (KC) * 32 + (16 << 8)); \
        short8 b2 = *(const short8*)(wp0 + (KC) * 32 + (32 << 8)); \
        short8 b3 = *(const short8*)(wp0 + (KC) * 32 + (48 << 8)); \
        acc0 = __builtin_amdgcn_mfma_f32_16x16x32_bf16(AF, b0, acc0, 0, 0, 0); \
        acc1 = __builtin_amdgcn_mfma_f32_16x16x32_bf16(AF, b1, acc1, 0, 0, 0); \
        acc2 = __builtin_amdgcn_mfma_f32_16x16x32_bf16(AF, b2, acc2, 0, 0, 0); \
        acc3 = __builtin_amdgcn_mfma_f32_16x16x32_bf16(AF, b3, acc3, 0, 0, 0); }
        DOKC(0, af0) DOKC(1, af1) DOKC(2, af2) DOKC(3, af3)
        DOKC(4, af4) DOKC(5, af5) DOKC(6, af6) DOKC(7, af7)
#undef DOKC
        // epilogue: (acc + bias) * 0.125 ; D: col=lane15, row=lgrp*4+r
        const int wrow = wave * 16 + lgrp * 4;
#define WCW(N, ACC) { \
        float b025 = bg[k * ZDIM + (N) * 16 + lane15] * 0.125f; \
        wc[wrow + 0][(N) * 16 + lane15] = fmaf(ACC[0], 0.125f, b025); \
        wc[wrow + 1][(N) * 16 + lane15] = fmaf(ACC[1], 0.125f, b025); \
        wc[wrow + 2][(N) * 16 + lane15] = fmaf(ACC[2], 0.125f, b025); \
        wc[wrow + 3][(N) * 16 + lane15] = fmaf(ACC[3], 0.125f, b025); }
        WCW(0, acc0) WCW(1, acc1) WCW(2, acc2) WCW(3, acc3)
#undef WCW
        __syncthreads();
        // coalesced bf16 store of the 32x64 tile
        {
            const int row = tid >> 2;
            const int q   = tid & 3;
            f32x4 v0 = *(const f32x4*)&wc[row][q * 16];
            f32x4 v1 = *(const f32x4*)&wc[row][q * 16 + 4];
            f32x4 v2 = *(const f32x4*)&wc[row][q * 16 + 8];
            f32x4 v3 = *(const f32x4*)&wc[row][q * 16 + 12];
            short8 s0 = cvt8(v0, v1);
            short8 s1 = cvt8(v2, v3);
            short* dst = Wcg + (((size_t)(k * 64 + su) * LEN) + (l0 + row)) * ZDIM + q * 16;
            *(short8*)dst = s0;
            *(short8*)(dst + 8) = s1;
        }
        __syncthreads();
    }
}

// ============ Kernel 2: gather + logits + LSE (quad-parallel) ============
// grid = 12288: s=bid&7 (XCD-local z); b2=bid>>3: lt=b2&31, u=(b2>>5)&7, k=b2>>8.
// 256 threads = 16 l-rows x 16 lanes; 16-lane group = 4 quads x 4 lanes.
// Per round jr (5 rounds): quad q handles j = jr*4+q; lane reads its 64B strip
// of the z row; dot16; 2 DPP quad adds; 1 exp per lane (amortized 4x).
__global__ __launch_bounds__(256) void cpc_loss(
    const float* __restrict__ zg, const short* __restrict__ Wcg,
    const int* __restrict__ bidx, const int* __restrict__ sidx,
    float* __restrict__ bins)
{
    __shared__ unsigned offs[16 * 18];   // z-row byte offsets per (lrow, j)
    __shared__ float red[8];

    const int tid = threadIdx.x;
    const int bid = blockIdx.x;
    const int s   = bid & 7;
    const int b2  = bid >> 3;
    const int lt  = b2 & 31;
    const int u   = (b2 >> 5) & 7;
    const int k   = b2 >> 8;
    const int l0  = lt * 16;
    const int su  = s * 8 + u;

    // precompute byte offsets; i = j*16 + lr so sidx reads are l-coalesced
    for (int i = tid; i < 288; i += 256) {
        int lr = i & 15;
        int j  = i >> 4;
        int l  = l0 + lr;
        unsigned row;
        if (j == 0) {
            row = (unsigned)(su * TDIM + (k + 1 + l));
        } else {
            int n  = j - 1;
            int bi = bidx[(k * U_N + u) * NNEG + n];
            int si = sidx[((((size_t)k * S_N + s) * U_N + u) * NNEG + n) * LEN + l];
            row = (unsigned)((s * 8 + bi) * TDIM + (k + 1 + si));
        }
        offs[lr * 18 + j] = row * (ZDIM * 4);
    }
    __syncthreads();

    const int lrow  = tid >> 4;
    const int c4    = tid & 15;
    const int quad  = c4 >> 2;
    const int qlane = c4 & 3;
    const int l     = l0 + lrow;

    // Wc strip: 16 floats (already scaled by 1/8)
    f32x4 w0, w1, w2, w3;
    {
        const short* wr = Wcg + (((size_t)(k * 64 + su) * LEN) + l) * ZDIM + qlane * 16;
        short8 h0 = *(const short8*)wr;
        short8 h1 = *(const short8*)(wr + 8);
        w0[0]=bf2f(h0[0]); w0[1]=bf2f(h0[1]); w0[2]=bf2f(h0[2]); w0[3]=bf2f(h0[3]);
        w1[0]=bf2f(h0[4]); w1[1]=bf2f(h0[5]); w1[2]=bf2f(h0[6]); w1[3]=bf2f(h0[7]);
        w2[0]=bf2f(h1[0]); w2[1]=bf2f(h1[1]); w2[2]=bf2f(h1[2]); w2[3]=bf2f(h1[3]);
        w3[0]=bf2f(h1[4]); w3[1]=bf2f(h1[5]); w3[2]=bf2f(h1[6]); w3[3]=bf2f(h1[7]);
    }

    const char* zb = (const char*)zg;
    float f0 = 0.f, mneg = -1e30f, se = 0.f;
    #pragma unroll
    for (int jr = 0; jr < 5; ++jr) {
        int j  = jr * 4 + quad;
        int jc = (j < 18) ? j : 17;
        unsigned off = offs[lrow * 18 + jc];
        const float* zp = (const float*)(zb + off) + qlane * 16;
        f32x4 z0 = *(const f32x4*)(zp);
        f32x4 z1 = *(const f32x4*)(zp + 4);
        f32x4 z2 = *(const f32x4*)(zp + 8);
        f32x4 z3 = *(const f32x4*)(zp + 12);
        float p = z0[0] * w0[0];
        p = fmaf(z0[1], w0[1], p); p = fmaf(z0[2], w0[2], p); p = fmaf(z0[3], w0[3], p);
        p = fmaf(z1[0], w1[0], p); p = fmaf(z1[1], w1[1], p);
        p = fmaf(z1[2], w1[2], p); p = fmaf(z1[3], w1[3], p);
        p = fmaf(z2[0], w2[0], p); p = fmaf(z2[1], w2[1], p);
        p = fmaf(z2[2], w2[2], p); p = fmaf(z2[3], w2[3], p);
        p = fmaf(z3[0], w3[0], p); p = fmaf(z3[1], w3[1], p);
        p = fmaf(z3[2], w3[2], p); p = fmaf(z3[3], w3[3], p);
        float f = qsum(p);                 // scale folded into Wc
        if (j >= 18) f = -1e30f;
        if (j == 0) f0 = f;
        else        mneg = fmaxf(mneg, f);
        se += __expf(f - 4.0f);            // |f| < ~2 for this data
    }
    // cross-quad (within-quad lanes identical -> xor4/xor8 sum one rep per quad)
    se += __shfl_xor(se, 4);  se += __shfl_xor(se, 8);
    mneg = fmaxf(mneg, __shfl_xor(mneg, 4));
    mneg = fmaxf(mneg, __shfl_xor(mneg, 8));

    float lossv = 0.f, accv = 0.f;
    if (c4 == 0) {
        lossv = (4.0f + __logf(se)) - f0;
        accv  = (f0 >= mneg) ? 1.f : 0.f;
    }
    lossv += __shfl_xor(lossv, 16); lossv += __shfl_xor(lossv, 32);
    accv  += __shfl_xor(accv, 16);  accv  += __shfl_xor(accv, 32);

    const int wave = tid >> 6;
    const int lane = tid & 63;
    if (lane == 0) { red[wave * 2] = lossv; red[wave * 2 + 1] = accv; }
    __syncthreads();
    if (tid == 0) atomicAdd(&bins[bid & 127], red[0] + red[2] + red[4] + red[6]);
    if (tid == 1) atomicAdd(&bins[128 + k * 128 + (bid & 127)],
                            red[1] + red[3] + red[5] + red[7]);
}

// ============ Kernel 3: reduce bins -> out[7] ============
__global__ void cpc_final(const float* __restrict__ bins, float* __restrict__ out)
{
    const int lane = threadIdx.x;  // 64
    float v = bins[lane] + bins[lane + 64];
    #pragma unroll
    for (int off = 1; off < 64; off <<= 1) v += __shfl_xor(v, off);
    if (lane == 0) out[0] = v * (1.0f / 196608.0f);
    #pragma unroll
    for (int k = 0; k < K_N; ++k) {
        const float* bk = bins + 128 + k * 128;
        float a = bk[lane] + bk[lane + 64];
        #pragma unroll
        for (int off = 1; off < 64; off <<= 1) a += __shfl_xor(a, off);
        if (lane == 0) out[1 + k] = a * (1.0f / 32768.0f);
    }
}

// ============ Fallback: r7 fused kernel (ws too small) ============
__global__ __launch_bounds__(256, 3) void cpc_fused(
    const float* __restrict__ zg, const float* __restrict__ cg_,
    const float* __restrict__ Wg, const float* __restrict__ bg,
    const int* __restrict__ bidx, const int* __restrict__ sidx,
    float* __restrict__ out)
{
    __shared__ __align__(16) short wlds[ZDIM * CDIM];
    __shared__ float wc[64][68];
    __shared__ float lds_red[8];

    const int tid = threadIdx.x;
    const int bid = blockIdx.x;
    const int lb  = (bid & 7) * 64 + (bid >> 3);
    const int su  = lb >> 3;
    const int lt8 = lb & 7;
    const int s   = su >> 3;
    const int u   = su & 7;
    const int l0  = lt8 * 64;

    const int wave   = tid >> 6;
    const int lane   = tid & 63;
    const int lane15 = lane & 15;
    const int lgrp   = lane >> 4;

    if (tid < 8) lds_red[tid] = 0.f;

    short8 af0, af1, af2, af3, af4, af5, af6, af7;
    {
        const int lrow = l0 + wave * 16 + lane15;
        const float* arow = cg_ + ((size_t)(su * TDIM + lrow)) * CDIM;
#define LDA(KC, AF) { \
        f32x4 a0_ = *(const f32x4*)(arow + (KC) * 32 + lgrp * 8); \
        f32x4 a1_ = *(const f32x4*)(arow + (KC) * 32 + lgrp * 8 + 4); \
        AF = cvt8(a0_, a1_); }
        LDA(0, af0) LDA(1, af1) LDA(2, af2) LDA(3, af3)
        LDA(4, af4) LDA(5, af5) LDA(6, af6) LDA(7, af7)
#undef LDA
    }

    float loss_acc = 0.f;
    for (int k = 0; k < K_N; ++k) {
        {
            const float* wbase = Wg + (size_t)k * ZDIM * CDIM;
            #pragma unroll
            for (int it = 0; it < 16; ++it) {
                int off = it * 1024 + tid * 4;
                int r = off >> 8;
                int c = off & 255;
                f32x4 v = *(const f32x4*)(wbase + off);
                short4v h;
                h.x = f2bf(v[0]); h.y = f2bf(v[1]); h.z = f2bf(v[2]); h.w = f2bf(v[3]);
                *(short4v*)&wlds[r * 256 + (((c >> 3) ^ (r & 7)) << 3) + ((c >> 2) & 1) * 4] = h;
            }
        }
        __syncthreads();
        {
            f32x4 acc0 = {0.f,0.f,0.f,0.f}, acc1 = {0.f,0.f,0.f,0.f};
            f32x4 acc2 = {0.f,0.f,0.f,0.f}, acc3 = {0.f,0.f,0.f,0.f};
            const int swb = lane15 & 7;
            const short* wl = &wlds[lane15 * 256];
#define DOKC(KC, AF) { \
            const int so = ((((KC) * 4 + lgrp) ^ swb) << 3); \
            acc0 = __builtin_amdgcn_mfma_f32_16x16x32_bf16(AF, *(const short8*)(wl + so),          acc0, 0, 0, 0); \
            acc1 = __builtin_amdgcn_mfma_f32_16x16x32_bf16(AF, *(const short8*)(wl + 16*256 + so), acc1, 0, 0, 0); \
            acc2 = __builtin_amdgcn_mfma_f32_16x16x32_bf16(AF, *(const short8*)(wl + 32*256 + so), acc2, 0, 0, 0); \
            acc3 = __builtin_amdgcn_mfma_f32_16x16x32_bf16(AF, *(const short8*)(wl + 48*256 + so), acc3, 0, 0, 0); }
            DOKC(0, af0) DOKC(1, af1) DOKC(2, af2) DOKC(3, af3)
            DOKC(4, af4) DOKC(5, af5) DOKC(6, af6) DOKC(7, af7)
#undef DOKC
            const int wrow = wave * 16 + lgrp * 4;
#define WCW(N, ACC) { \
            float bias_ = bg[k * ZDIM + (N) * 16 + lane15]; \
            wc[wrow + 0][(N) * 16 + lane15] = ACC[0] + bias_; \
            wc[wrow + 1][(N) * 16 + lane15] = ACC[1] + bias_; \
            wc[wrow + 2][(N) * 16 + lane15] = ACC[2] + bias_; \
            wc[wrow + 3][(N) * 16 + lane15] = ACC[3] + bias_; }
            WCW(0, acc0) WCW(1, acc1) WCW(2, acc2) WCW(3, acc3)
#undef WCW
        }
        __syncthreads();

        const int lt = tid >> 2;
        const int jq = tid & 3;
        const int l  = l0 + lt;
        float fv[5];
        #pragma unroll
        for (int t = 0; t < 5; ++t) {
            int j = jq + 4 * t;
            if (j >= 18) { fv[t] = -1e30f; continue; }
            const float* zp;
            if (j == 0) {
                zp = zg + ((size_t)(su * TDIM + (k + 1 + l))) * ZDIM;
            } else {
                int n  = j - 1;
                int bi = bidx[(k * U_N + u) * NNEG + n];
                int si = sidx[(size_t)((((k * S_N + s) * U_N + u) * NNEG + n)) * LEN + l];
                zp = zg + ((size_t)((s * U_N + bi) * TDIM + (k + 1 + si))) * ZDIM;
            }
            float f = 0.f;
            const float* wr = &wc[lt][0];
            #pragma unroll
            for (int c4i = 0; c4i < 16; ++c4i) {
                f32x4 zv = *(const f32x4*)(zp + c4i * 4);
                f32x4 wv = *(const f32x4*)(wr + c4i * 4);
                f = fmaf(zv[0], wv[0], f); f = fmaf(zv[1], wv[1], f);
                f = fmaf(zv[2], wv[2], f); f = fmaf(zv[3], wv[3], f);
            }
            fv[t] = f * 0.125f;
        }
        float mall = -1e30f, mneg = -1e30f;
        #pragma unroll
        for (int t = 0; t < 5; ++t) {
            mall = fmaxf(mall, fv[t]);
            bool skip = (jq == 0 && t == 0) || (jq + 4 * t >= 18);
            if (!skip) mneg = fmaxf(mneg, fv[t]);
        }
        mall = fmaxf(mall, __shfl_xor(mall, 1));
        mall = fmaxf(mall, __shfl_xor(mall, 2));
        mneg = fmaxf(mneg, __shfl_xor(mneg, 1));
        mneg = fmaxf(mneg, __shfl_xor(mneg, 2));
        float se = 0.f;
        #pragma unroll
        for (int t = 0; t < 5; ++t)
            if (jq + 4 * t < 18) se += __expf(fv[t] - mall);
        se += __shfl_xor(se, 1);
        se += __shfl_xor(se, 2);
        float lossv = 0.f, accv = 0.f;
        if (jq == 0) {
            lossv = (mall + __logf(se)) - fv[0];
            accv  = (fv[0] >= mneg) ? 1.f : 0.f;
        }
        loss_acc += lossv;
        #pragma unroll
        for (int off = 1; off < 64; off <<= 1) accv += __shfl_xor(accv, off);
        if (lane == 0) atomicAdd(&lds_red[1 + k], accv);
    }
    #pragma unroll
    for (int off = 1; off < 64; off <<= 1) loss_acc += __shfl_xor(loss_acc, off);
    if (lane == 0) atomicAdd(&lds_red[0], loss_acc);
    __syncthreads();
    if (tid == 0) atomicAdd(out, lds_red[0] * (1.0f / 196608.0f));
    if (tid >= 8 && tid < 8 + K_N)
        atomicAdd(out + 1 + (tid - 8), lds_red[1 + (tid - 8)] * (1.0f / 32768.0f));
}

extern "C" void kernel_launch(void* const* d_in, const int* in_sizes, int n_in,
                              void* d_out, int out_size, void* d_ws, size_t ws_size,
                              hipStream_t stream) {
    const float* z = (const float*)d_in[0];
    const float* c = (const float*)d_in[1];
    const float* W = (const float*)d_in[2];
    const float* b = (const float*)d_in[3];
    const int* batch_index = (const int*)d_in[4];
    const int* seq_index   = (const int*)d_in[5];
    float* out = (float*)d_out;

    const size_t WBF_BYTES  = (size_t)K_N * ZDIM * CDIM * sizeof(short);      // 196,608
    const size_t WCG_BYTES  = (size_t)K_N * 64 * LEN * ZDIM * sizeof(short);  // 25.2 MB
    const size_t BINS_FLOATS = 7 * 128;

    if (ws_size >= WBF_BYTES + WCG_BYTES + BINS_FLOATS * sizeof(float)) {
        short* wbf  = (short*)d_ws;
        short* Wcg  = (short*)((char*)d_ws + WBF_BYTES);
        float* bins = (float*)((char*)d_ws + WBF_BYTES + WCG_BYTES);
        hipMemsetAsync(bins, 0, BINS_FLOATS * sizeof(float), stream);
        cpc_wcvt<<<dim3(96), dim3(256), 0, stream>>>(W, wbf);
        cpc_gemm<<<dim3(1024), dim3(128), 0, stream>>>(c, wbf, b, Wcg);
        cpc_loss<<<dim3(12288), dim3(256), 0, stream>>>(z, Wcg, batch_index, seq_index, bins);
        cpc_final<<<dim3(1), dim3(64), 0, stream>>>(bins, out);
    } else {
        hipMemsetAsync(out, 0, 7 * sizeof(float), stream);
        cpc_fused<<<dim3(512), dim3(256), 0, stream>>>(z, c, W, b, batch_index, seq_index, out);
    }
}

// Round 15
// 164.889 us; speedup vs baseline: 1.3714x; 1.3714x over previous
//
#include <hip/hip_runtime.h>
#include <math.h>

#define S_N 8
#define U_N 8
#define K_N 6
#define NNEG 17
#define ZDIM 64
#define CDIM 256
#define LEN 512
#define TDIM (LEN + K_N)   // 518

typedef __attribute__((ext_vector_type(8))) short short8;
typedef __attribute__((ext_vector_type(4))) short short4v;
typedef __attribute__((ext_vector_type(4))) float f32x4;

__device__ __forceinline__ short f2bf(float x) {
    unsigned u = __builtin_bit_cast(unsigned, x);
    return (short)((u + 0x7fffu + ((u >> 16) & 1u)) >> 16);   // RNE
}
__device__ __forceinline__ float bf2f(short h) {
    unsigned u = ((unsigned)(unsigned short)h) << 16;
    return __builtin_bit_cast(float, u);
}
__device__ __forceinline__ short8 cvt8(f32x4 a, f32x4 b) {
    short8 r;
    r[0] = f2bf(a[0]); r[1] = f2bf(a[1]); r[2] = f2bf(a[2]); r[3] = f2bf(a[3]);
    r[4] = f2bf(b[0]); r[5] = f2bf(b[1]); r[6] = f2bf(b[2]); r[7] = f2bf(b[3]);
    return r;
}
// 16-lane butterfly sum, pure VALU via DPP:
// quad_perm xor1 (0xB1), xor2 (0x4E), ROW_HALF_MIRROR (0x141), ROW_MIRROR (0x140)
__device__ __forceinline__ float sum16(float x) {
    int a = __builtin_bit_cast(int, x);
    float y = x + __builtin_bit_cast(float, __builtin_amdgcn_mov_dpp(a, 0xB1, 0xF, 0xF, true));
    a = __builtin_bit_cast(int, y);
    y = y + __builtin_bit_cast(float, __builtin_amdgcn_mov_dpp(a, 0x4E, 0xF, 0xF, true));
    a = __builtin_bit_cast(int, y);
    y = y + __builtin_bit_cast(float, __builtin_amdgcn_mov_dpp(a, 0x141, 0xF, 0xF, true));
    a = __builtin_bit_cast(int, y);
    y = y + __builtin_bit_cast(float, __builtin_amdgcn_mov_dpp(a, 0x140, 0xF, 0xF, true));
    return y;
}

// ============ Kernel 0: W f32 -> bf16 (once) ============
__global__ __launch_bounds__(256) void cpc_wcvt(const float* __restrict__ Wg,
                                                short* __restrict__ wbf)
{
    int i4 = (blockIdx.x * 256 + threadIdx.x) * 4;   // < 98304
    f32x4 v = *(const f32x4*)(Wg + i4);
    short4v h;
    h.x = f2bf(v[0]); h.y = f2bf(v[1]); h.z = f2bf(v[2]); h.w = f2bf(v[3]);
    *(short4v*)(wbf + i4) = h;
}

// ============ Kernel 1: Wc GEMM -> workspace (bf16, pre-scaled by 1/8) ============
// r8 structure: grid = 64 su * 8 ltiles = 512 blocks, 256 threads (4 waves),
// A preloaded once to regs, W[k] staged bf16->LDS swizzled (now from wbf,
// 8 iters of short8, no cvt).
__global__ __launch_bounds__(256, 3) void cpc_gemm(
    const float* __restrict__ cg_, const short* __restrict__ wbf,
    const float* __restrict__ bg, short* __restrict__ Wcg)
{
    __shared__ __align__(16) short wlds[ZDIM * CDIM];
    __shared__ float wc[64][68];

    const int tid = threadIdx.x;
    const int bid = blockIdx.x;
    const int su  = bid >> 3;
    const int lt8 = bid & 7;
    const int l0  = lt8 * 64;

    const int wave   = tid >> 6;
    const int lane   = tid & 63;
    const int lane15 = lane & 15;
    const int lgrp   = lane >> 4;

    // preload A fragments once (named regs)
    short8 af0, af1, af2, af3, af4, af5, af6, af7;
    {
        const int lrow = l0 + wave * 16 + lane15;
        const float* arow = cg_ + ((size_t)(su * TDIM + lrow)) * CDIM;
#define LDA(KC, AF) { \
        f32x4 a0_ = __builtin_nontemporal_load((const f32x4*)(arow + (KC) * 32 + lgrp * 8)); \
        f32x4 a1_ = __builtin_nontemporal_load((const f32x4*)(arow + (KC) * 32 + lgrp * 8 + 4)); \
        AF = cvt8(a0_, a1_); }
        LDA(0, af0) LDA(1, af1) LDA(2, af2) LDA(3, af3)
        LDA(4, af4) LDA(5, af5) LDA(6, af6) LDA(7, af7)
#undef LDA
    }

    for (int k = 0; k < K_N; ++k) {
        // stage W[k] bf16 -> LDS, swizzled; 8 iters of 16B per thread
        {
            const short* wkb = wbf + k * (ZDIM * CDIM);
            #pragma unroll
            for (int it = 0; it < 8; ++it) {
                int ch = it * 256 + tid;        // 16B-chunk index in 64x256 bf16
                int r  = ch >> 5;               // z row (32 chunks/row)
                int cc = ch & 31;               // chunk within row
                short8 h = *(const short8*)(wkb + r * 256 + cc * 8);
                *(short8*)&wlds[r * 256 + ((cc ^ (r & 7)) << 3)] = h;
            }
        }
        __syncthreads();

        // MFMA
        {
            f32x4 acc0 = {0.f,0.f,0.f,0.f}, acc1 = {0.f,0.f,0.f,0.f};
            f32x4 acc2 = {0.f,0.f,0.f,0.f}, acc3 = {0.f,0.f,0.f,0.f};
            const int swb = lane15 & 7;
            const short* wl = &wlds[lane15 * 256];
#define DOKC(KC, AF) { \
            const int so = ((((KC) * 4 + lgrp) ^ swb) << 3); \
            acc0 = __builtin_amdgcn_mfma_f32_16x16x32_bf16(AF, *(const short8*)(wl + so),          acc0, 0, 0, 0); \
            acc1 = __builtin_amdgcn_mfma_f32_16x16x32_bf16(AF, *(const short8*)(wl + 16*256 + so), acc1, 0, 0, 0); \
            acc2 = __builtin_amdgcn_mfma_f32_16x16x32_bf16(AF, *(const short8*)(wl + 32*256 + so), acc2, 0, 0, 0); \
            acc3 = __builtin_amdgcn_mfma_f32_16x16x32_bf16(AF, *(const short8*)(wl + 48*256 + so), acc3, 0, 0, 0); }
            DOKC(0, af0) DOKC(1, af1) DOKC(2, af2) DOKC(3, af3)
            DOKC(4, af4) DOKC(5, af5) DOKC(6, af6) DOKC(7, af7)
#undef DOKC
            // epilogue: (acc + bias) * 0.125  (scale folded into Wc)
            const int wrow = wave * 16 + lgrp * 4;
#define WCW(N, ACC) { \
            float b025 = bg[k * ZDIM + (N) * 16 + lane15] * 0.125f; \
            wc[wrow + 0][(N) * 16 + lane15] = fmaf(ACC[0], 0.125f, b025); \
            wc[wrow + 1][(N) * 16 + lane15] = fmaf(ACC[1], 0.125f, b025); \
            wc[wrow + 2][(N) * 16 + lane15] = fmaf(ACC[2], 0.125f, b025); \
            wc[wrow + 3][(N) * 16 + lane15] = fmaf(ACC[3], 0.125f, b025); }
            WCW(0, acc0) WCW(1, acc1) WCW(2, acc2) WCW(3, acc3)
#undef WCW
        }
        __syncthreads();

        // coalesced bf16 store of the 64x64 Wc tile
        {
            const int row = tid >> 2;
            const int q   = tid & 3;
            f32x4 v0 = *(const f32x4*)&wc[row][q * 16];
            f32x4 v1 = *(const f32x4*)&wc[row][q * 16 + 4];
            f32x4 v2 = *(const f32x4*)&wc[row][q * 16 + 8];
            f32x4 v3 = *(const f32x4*)&wc[row][q * 16 + 12];
            short8 s0 = cvt8(v0, v1);
            short8 s1 = cvt8(v2, v3);
            short* dst = Wcg + (((size_t)(k * 64 + su) * LEN) + (l0 + row)) * ZDIM + q * 16;
            *(short8*)dst = s0;
            *(short8*)(dst + 8) = s1;
        }
        __syncthreads();
    }
}

// ============ Kernel 2: gather + logits + LSE (r8 structure + DPP reduce) ============
// grid = 12288: s=bid&7 (XCD-local z); b2=bid>>3: lt=b2&31, u=(b2>>5)&7, k=b2>>8.
// 256 threads = 16 l-rows x 16 lanes.  Per j (18 serial, independent streams):
// lane reads 16B of the z row (256B coalesced per group), dot4, 16-lane DPP
// butterfly sum (pure VALU), exp with fixed shift 4.
__global__ __launch_bounds__(256) void cpc_loss(
    const float* __restrict__ zg, const short* __restrict__ Wcg,
    const int* __restrict__ bidx, const int* __restrict__ sidx,
    float* __restrict__ bins)
{
    __shared__ int bi_sh[NNEG];
    __shared__ int si_sh[16 * NNEG];
    __shared__ float red[8];

    const int tid = threadIdx.x;
    const int bid = blockIdx.x;
    const int s   = bid & 7;
    const int b2  = bid >> 3;
    const int lt  = b2 & 31;
    const int u   = (b2 >> 5) & 7;
    const int k   = b2 >> 8;
    const int l0  = lt * 16;
    const int su  = s * 8 + u;

    if (tid < NNEG) bi_sh[tid] = bidx[(k * U_N + u) * NNEG + tid];
    for (int i = tid; i < 16 * NNEG; i += 256) {
        int lr = i / NNEG;
        int n  = i - lr * NNEG;
        si_sh[i] = sidx[((((size_t)k * S_N + s) * U_N + u) * NNEG + n) * LEN + (l0 + lr)];
    }
    __syncthreads();

    const int lrow = tid >> 4;
    const int c4   = tid & 15;
    const int l    = l0 + lrow;

    // Wc fragment (pre-scaled by 1/8): 4 consecutive z-values per lane
    f32x4 wcv;
    {
        const short* wrow = Wcg + (((size_t)(k * 64 + su) * LEN) + l) * ZDIM + c4 * 4;
        short4v wb = __builtin_nontemporal_load((const short4v*)wrow);
        wcv[0] = bf2f(wb.x); wcv[1] = bf2f(wb.y); wcv[2] = bf2f(wb.z); wcv[3] = bf2f(wb.w);
    }

    float f0 = 0.f, mneg = -1e30f, se = 0.f;
    #pragma unroll 6
    for (int j = 0; j < 18; ++j) {
        size_t zrow;
        if (j == 0) {
            zrow = (size_t)su * TDIM + (k + 1 + l);
        } else {
            int n  = j - 1;
            int bi = bi_sh[n];
            int si = si_sh[lrow * NNEG + n];
            zrow = (size_t)(s * 8 + bi) * TDIM + (k + 1 + si);
        }
        f32x4 zv = *(const f32x4*)(zg + zrow * ZDIM + c4 * 4);
        float p = zv[0] * wcv[0];
        p = fmaf(zv[1], wcv[1], p);
        p = fmaf(zv[2], wcv[2], p);
        p = fmaf(zv[3], wcv[3], p);
        float f = sum16(p);                 // scale folded into Wc
        if (j == 0) f0 = f; else mneg = fmaxf(mneg, f);
        se += __expf(f - 4.0f);             // |f| << 4 for this data
    }

    float lossv = (4.0f + __logf(se)) - f0;
    float accv  = (f0 >= mneg) ? 1.f : 0.f;
    if (c4 != 0) { lossv = 0.f; accv = 0.f; }
    lossv += __shfl_xor(lossv, 16); lossv += __shfl_xor(lossv, 32);
    accv  += __shfl_xor(accv, 16);  accv  += __shfl_xor(accv, 32);

    const int wave = tid >> 6;
    const int lane = tid & 63;
    if (lane == 0) { red[wave * 2] = lossv; red[wave * 2 + 1] = accv; }
    __syncthreads();
    if (tid == 0) atomicAdd(&bins[bid & 127], red[0] + red[2] + red[4] + red[6]);
    if (tid == 1) atomicAdd(&bins[128 + k * 128 + (bid & 127)],
                            red[1] + red[3] + red[5] + red[7]);
}

// ============ Kernel 3: reduce bins -> out[7] ============
__global__ void cpc_final(const float* __restrict__ bins, float* __restrict__ out)
{
    const int lane = threadIdx.x;  // 64
    float v = bins[lane] + bins[lane + 64];
    #pragma unroll
    for (int off = 1; off < 64; off <<= 1) v += __shfl_xor(v, off);
    if (lane == 0) out[0] = v * (1.0f / 196608.0f);
    #pragma unroll
    for (int k = 0; k < K_N; ++k) {
        const float* bk = bins + 128 + k * 128;
        float a = bk[lane] + bk[lane + 64];
        #pragma unroll
        for (int off = 1; off < 64; off <<= 1) a += __shfl_xor(a, off);
        if (lane == 0) out[1 + k] = a * (1.0f / 32768.0f);
    }
}

// ============ Fallback: fused kernel (ws too small) ============
__global__ __launch_bounds__(256, 3) void cpc_fused(
    const float* __restrict__ zg, const float* __restrict__ cg_,
    const float* __restrict__ Wg, const float* __restrict__ bg,
    const int* __restrict__ bidx, const int* __restrict__ sidx,
    float* __restrict__ out)
{
    __shared__ __align__(16) short wlds[ZDIM * CDIM];
    __shared__ float wc[64][68];
    __shared__ float lds_red[8];

    const int tid = threadIdx.x;
    const int bid = blockIdx.x;
    const int lb  = (bid & 7) * 64 + (bid >> 3);
    const int su  = lb >> 3;
    const int lt8 = lb & 7;
    const int s   = su >> 3;
    const int u   = su & 7;
    const int l0  = lt8 * 64;

    const int wave   = tid >> 6;
    const int lane   = tid & 63;
    const int lane15 = lane & 15;
    const int lgrp   = lane >> 4;

    if (tid < 8) lds_red[tid] = 0.f;

    short8 af0, af1, af2, af3, af4, af5, af6, af7;
    {
        const int lrow = l0 + wave * 16 + lane15;
        const float* arow = cg_ + ((size_t)(su * TDIM + lrow)) * CDIM;
#define LDA(KC, AF) { \
        f32x4 a0_ = *(const f32x4*)(arow + (KC) * 32 + lgrp * 8); \
        f32x4 a1_ = *(const f32x4*)(arow + (KC) * 32 + lgrp * 8 + 4); \
        AF = cvt8(a0_, a1_); }
        LDA(0, af0) LDA(1, af1) LDA(2, af2) LDA(3, af3)
        LDA(4, af4) LDA(5, af5) LDA(6, af6) LDA(7, af7)
#undef LDA
    }

    float loss_acc = 0.f;
    for (int k = 0; k < K_N; ++k) {
        {
            const float* wbase = Wg + (size_t)k * ZDIM * CDIM;
            #pragma unroll
            for (int it = 0; it < 16; ++it) {
                int off = it * 1024 + tid * 4;
                int r = off >> 8;
                int c = off & 255;
                f32x4 v = *(const f32x4*)(wbase + off);
                short4v h;
                h.x = f2bf(v[0]); h.y = f2bf(v[1]); h.z = f2bf(v[2]); h.w = f2bf(v[3]);
                *(short4v*)&wlds[r * 256 + (((c >> 3) ^ (r & 7)) << 3) + ((c >> 2) & 1) * 4] = h;
            }
        }
        __syncthreads();
        {
            f32x4 acc0 = {0.f,0.f,0.f,0.f}, acc1 = {0.f,0.f,0.f,0.f};
            f32x4 acc2 = {0.f,0.f,0.f,0.f}, acc3 = {0.f,0.f,0.f,0.f};
            const int swb = lane15 & 7;
            const short* wl = &wlds[lane15 * 256];
#define DOKC(KC, AF) { \
            const int so = ((((KC) * 4 + lgrp) ^ swb) << 3); \
            acc0 = __builtin_amdgcn_mfma_f32_16x16x32_bf16(AF, *(const short8*)(wl + so),          acc0, 0, 0, 0); \
            acc1 = __builtin_amdgcn_mfma_f32_16x16x32_bf16(AF, *(const short8*)(wl + 16*256 + so), acc1, 0, 0, 0); \
            acc2 = __builtin_amdgcn_mfma_f32_16x16x32_bf16(AF, *(const short8*)(wl + 32*256 + so), acc2, 0, 0, 0); \
            acc3 = __builtin_amdgcn_mfma_f32_16x16x32_bf16(AF, *(const short8*)(wl + 48*256 + so), acc3, 0, 0, 0); }
            DOKC(0, af0) DOKC(1, af1) DOKC(2, af2) DOKC(3, af3)
            DOKC(4, af4) DOKC(5, af5) DOKC(6, af6) DOKC(7, af7)
#undef DOKC
            const int wrow = wave * 16 + lgrp * 4;
#define WCW(N, ACC) { \
            float bias_ = bg[k * ZDIM + (N) * 16 + lane15]; \
            wc[wrow + 0][(N) * 16 + lane15] = ACC[0] + bias_; \
            wc[wrow + 1][(N) * 16 + lane15] = ACC[1] + bias_; \
            wc[wrow + 2][(N) * 16 + lane15] = ACC[2] + bias_; \
            wc[wrow + 3][(N) * 16 + lane15] = ACC[3] + bias_; }
            WCW(0, acc0) WCW(1, acc1) WCW(2, acc2) WCW(3, acc3)
#undef WCW
        }
        __syncthreads();

        const int lt = tid >> 2;
        const int jq = tid & 3;
        const int l  = l0 + lt;
        float fv[5];
        #pragma unroll
        for (int t = 0; t < 5; ++t) {
            int j = jq + 4 * t;
            if (j >= 18) { fv[t] = -1e30f; continue; }
            const float* zp;
            if (j == 0) {
                zp = zg + ((size_t)(su * TDIM + (k + 1 + l))) * ZDIM;
            } else {
                int n  = j - 1;
                int bi = bidx[(k * U_N + u) * NNEG + n];
                int si = sidx[(size_t)((((k * S_N + s) * U_N + u) * NNEG + n)) * LEN + l];
                zp = zg + ((size_t)((s * U_N + bi) * TDIM + (k + 1 + si))) * ZDIM;
            }
            float f = 0.f;
            const float* wr = &wc[lt][0];
            #pragma unroll
            for (int c4i = 0; c4i < 16; ++c4i) {
                f32x4 zv = *(const f32x4*)(zp + c4i * 4);
                f32x4 wv = *(const f32x4*)(wr + c4i * 4);
                f = fmaf(zv[0], wv[0], f); f = fmaf(zv[1], wv[1], f);
                f = fmaf(zv[2], wv[2], f); f = fmaf(zv[3], wv[3], f);
            }
            fv[t] = f * 0.125f;
        }
        float mall = -1e30f, mneg = -1e30f;
        #pragma unroll
        for (int t = 0; t < 5; ++t) {
            mall = fmaxf(mall, fv[t]);
            bool skip = (jq == 0 && t == 0) || (jq + 4 * t >= 18);
            if (!skip) mneg = fmaxf(mneg, fv[t]);
        }
        mall = fmaxf(mall, __shfl_xor(mall, 1));
        mall = fmaxf(mall, __shfl_xor(mall, 2));
        mneg = fmaxf(mneg, __shfl_xor(mneg, 1));
        mneg = fmaxf(mneg, __shfl_xor(mneg, 2));
        float se = 0.f;
        #pragma unroll
        for (int t = 0; t < 5; ++t)
            if (jq + 4 * t < 18) se += __expf(fv[t] - mall);
        se += __shfl_xor(se, 1);
        se += __shfl_xor(se, 2);
        float lossv = 0.f, accv = 0.f;
        if (jq == 0) {
            lossv = (mall + __logf(se)) - fv[0];
            accv  = (fv[0] >= mneg) ? 1.f : 0.f;
        }
        loss_acc += lossv;
        #pragma unroll
        for (int off = 1; off < 64; off <<= 1) accv += __shfl_xor(accv, off);
        if (lane == 0) atomicAdd(&lds_red[1 + k], accv);
    }
    #pragma unroll
    for (int off = 1; off < 64; off <<= 1) loss_acc += __shfl_xor(loss_acc, off);
    if (lane == 0) atomicAdd(&lds_red[0], loss_acc);
    __syncthreads();
    if (tid == 0) atomicAdd(out, lds_red[0] * (1.0f / 196608.0f));
    if (tid >= 8 && tid < 8 + K_N)
        atomicAdd(out + 1 + (tid - 8), lds_red[1 + (tid - 8)] * (1.0f / 32768.0f));
}

extern "C" void kernel_launch(void* const* d_in, const int* in_sizes, int n_in,
                              void* d_out, int out_size, void* d_ws, size_t ws_size,
                              hipStream_t stream) {
    const float* z = (const float*)d_in[0];
    const float* c = (const float*)d_in[1];
    const float* W = (const float*)d_in[2];
    const float* b = (const float*)d_in[3];
    const int* batch_index = (const int*)d_in[4];
    const int* seq_index   = (const int*)d_in[5];
    float* out = (float*)d_out;

    const size_t WBF_BYTES  = (size_t)K_N * ZDIM * CDIM * sizeof(short);      // 196,608
    const size_t WCG_BYTES  = (size_t)K_N * 64 * LEN * ZDIM * sizeof(short);  // 25.2 MB
    const size_t BINS_FLOATS = 7 * 128;

    if (ws_size >= WBF_BYTES + WCG_BYTES + BINS_FLOATS * sizeof(float)) {
        short* wbf  = (short*)d_ws;
        short* Wcg  = (short*)((char*)d_ws + WBF_BYTES);
        float* bins = (float*)((char*)d_ws + WBF_BYTES + WCG_BYTES);
        hipMemsetAsync(bins, 0, BINS_FLOATS * sizeof(float), stream);
        cpc_wcvt<<<dim3(96), dim3(256), 0, stream>>>(W, wbf);
        cpc_gemm<<<dim3(512), dim3(256), 0, stream>>>(c, wbf, b, Wcg);
        cpc_loss<<<dim3(12288), dim3(256), 0, stream>>>(z, Wcg, batch_index, seq_index, bins);
        cpc_final<<<dim3(1), dim3(64), 0, stream>>>(bins, out);
    } else {
        hipMemsetAsync(out, 0, 7 * sizeof(float), stream);
        cpc_fused<<<dim3(512), dim3(256), 0, stream>>>(z, c, W, b, batch_index, seq_index, out);
    }
}